// Round 4
// baseline (1053.117 us; speedup 1.0000x reference)
//
#include <hip/hip_runtime.h>

#define Bsz 16
#define Nn  100000
#define Ee  2000000
#define Dd  512
#define Cc  10
#define NB  (Nn * Bsz)
#define SCAN_BLK 1024
#define NSB ((Nn + SCAN_BLK - 1) / SCAN_BLK)   // 98

// ---- ordered-uint encoding for float atomic min/max ----
__device__ __forceinline__ unsigned enc_f(float f) {
    unsigned u = __float_as_uint(f);
    return (u & 0x80000000u) ? ~u : (u | 0x80000000u);
}
__device__ __forceinline__ float dec_f(unsigned e) {
    unsigned u = (e & 0x80000000u) ? (e ^ 0x80000000u) : ~e;
    return __uint_as_float(u);
}

// transpose x (B,N) -> xb[n*16+b]; thr[n]=|nt[n]|; zero histogram; init 4 passes' minmax slots
__global__ void prep(const float* __restrict__ x, const float* __restrict__ nt,
                     float* __restrict__ xb, float* __restrict__ thr,
                     int* __restrict__ cnt, unsigned* __restrict__ mm) {
    int i = blockIdx.x * blockDim.x + threadIdx.x;
    if (i < NB) {
        int n = i >> 4, b = i & 15;
        xb[i] = x[b * Nn + n];
    }
    if (i < Nn) { thr[i] = fabsf(nt[i]); cnt[i] = 0; }
    if (i < 8)  { mm[i] = (i & 1) ? 0u : 0xFFFFFFFFu; }
}

__global__ void hist(const int* __restrict__ dstv, int* __restrict__ cnt) {
    int e = blockIdx.x * blockDim.x + threadIdx.x;
    if (e < Ee) atomicAdd(&cnt[dstv[e]], 1);
}

// per-block inclusive scan (Hillis-Steele) + block sums
__global__ void scan1(const int* __restrict__ cnt, int* __restrict__ incl,
                      int* __restrict__ bsum) {
    __shared__ int s[SCAN_BLK];
    int i = blockIdx.x * SCAN_BLK + threadIdx.x;
    int v = (i < Nn) ? cnt[i] : 0;
    s[threadIdx.x] = v;
    __syncthreads();
    for (int off = 1; off < SCAN_BLK; off <<= 1) {
        int t = (threadIdx.x >= off) ? s[threadIdx.x - off] : 0;
        __syncthreads();
        s[threadIdx.x] += t;
        __syncthreads();
    }
    if (i < Nn) incl[i] = s[threadIdx.x];
    if (threadIdx.x == SCAN_BLK - 1) bsum[blockIdx.x] = s[threadIdx.x];
}

__global__ void scan2(const int* __restrict__ bsum, int* __restrict__ bofs) {
    if (threadIdx.x == 0) {
        int acc = 0;
        for (int k = 0; k < NSB; k++) { bofs[k] = acc; acc += bsum[k]; }
    }
}

// exclusive row offsets + scatter cursors
__global__ void scan3(const int* __restrict__ cnt, const int* __restrict__ incl,
                      const int* __restrict__ bofs, int* __restrict__ row,
                      int* __restrict__ cur) {
    int i = blockIdx.x * blockDim.x + threadIdx.x;
    if (i < Nn) {
        int excl = incl[i] - cnt[i] + bofs[i / SCAN_BLK];
        row[i] = excl;
        cur[i] = excl;
    }
    if (i == 0) row[Nn] = Ee;
}

// permute edges into CSR-by-dst; fold in w = ew * tanh(mult) (computed once total)
__global__ void build(const int* __restrict__ srcv, const int* __restrict__ dstv,
                      const float* __restrict__ ew, const float* __restrict__ mult,
                      int* __restrict__ cur, int* __restrict__ csr_src,
                      float* __restrict__ csr_w) {
    int e = blockIdx.x * blockDim.x + threadIdx.x;
    if (e < Ee) {
        int d = dstv[e];
        int pos = atomicAdd(&cur[d], 1);
        csr_src[pos] = srcv[e];
        csr_w[pos]   = ew[e] * tanhf(mult[e]);
    }
}

// thread = (node, batch): sum in-edges (no atomics), fused block min/max reduce
__global__ void gather(const int* __restrict__ row, const int* __restrict__ csr_src,
                       const float* __restrict__ csr_w, const float* __restrict__ xb,
                       float* __restrict__ aggr, unsigned* __restrict__ mm) {
    int i = blockIdx.x * 256 + threadIdx.x;   // grid is exact: NB/256 blocks
    int n = i >> 4, b = i & 15;
    int ks = row[n], ke = row[n + 1];
    float acc = 0.0f;
    for (int k = ks; k < ke; k++)
        acc += xb[csr_src[k] * 16 + b] * csr_w[k];
    aggr[i] = acc;

    float lmin = acc, lmax = acc;
    #pragma unroll
    for (int off = 32; off > 0; off >>= 1) {
        lmin = fminf(lmin, __shfl_down(lmin, off));
        lmax = fmaxf(lmax, __shfl_down(lmax, off));
    }
    __shared__ float smin[4], smax[4];
    int wid = threadIdx.x >> 6, lane = threadIdx.x & 63;
    if (lane == 0) { smin[wid] = lmin; smax[wid] = lmax; }
    __syncthreads();
    if (threadIdx.x == 0) {
        float m0 = smin[0], M0 = smax[0];
        #pragma unroll
        for (int k = 1; k < 4; k++) { m0 = fminf(m0, smin[k]); M0 = fmaxf(M0, smax[k]); }
        atomicMin(&mm[0], enc_f(m0));
        atomicMax(&mm[1], enc_f(M0));
    }
}

__global__ void update(const float* __restrict__ aggr, const float* __restrict__ thr,
                       const unsigned* __restrict__ mm, float* __restrict__ xb) {
    int i = blockIdx.x * blockDim.x + threadIdx.x;
    if (i < NB) {
        float amin = dec_f(mm[0]), amax = dec_f(mm[1]);
        float inv = 1.0f / (amax - amin);
        int n = i >> 4;
        float v = (aggr[i] - amin) * inv - thr[n];
        xb[i] = 1.0f / (1.0f + expf(-v));
    }
}

// gather decision nodes + (16x512)@(512x10) matmul, single block of 512 threads
__global__ void final_k(const float* __restrict__ xb, const int* __restrict__ dix,
                        const float* __restrict__ fcw, const float* __restrict__ fcb,
                        float* __restrict__ out) {
    __shared__ float xd[Dd][Bsz];   // 32 KB
    int j = threadIdx.x;
    int n = dix[j];
    #pragma unroll
    for (int b = 0; b < Bsz; b++) xd[j][b] = xb[n * 16 + b];
    __syncthreads();
    if (j < Bsz * Cc) {
        int b = j / Cc, c = j % Cc;
        float acc = fcb[c];
        for (int k = 0; k < Dd; k++) acc += xd[k][b] * fcw[c * Dd + k];
        out[b * Cc + c] = acc;
    }
}

extern "C" void kernel_launch(void* const* d_in, const int* in_sizes, int n_in,
                              void* d_out, int out_size, void* d_ws, size_t ws_size,
                              hipStream_t stream) {
    const float* x    = (const float*)d_in[0];
    const float* ew   = (const float*)d_in[1];
    const float* mult = (const float*)d_in[2];
    const float* nt   = (const float*)d_in[3];
    const float* fcw  = (const float*)d_in[4];
    const float* fcb  = (const float*)d_in[5];
    const int*   ei   = (const int*)d_in[6];
    const int*   dix  = (const int*)d_in[7];
    float* out = (float*)d_out;

    const int* srcv = ei;
    const int* dstv = ei + Ee;

    // workspace layout
    float* xb      = (float*)d_ws;             // NB
    float* aggr    = xb + NB;                  // NB
    float* thr     = aggr + NB;                // Nn
    float* csr_w   = thr + Nn;                 // Ee
    int*   csr_src = (int*)(csr_w + Ee);       // Ee
    int*   row     = csr_src + Ee;             // Nn+1
    int*   cur     = row + Nn + 1;             // Nn
    int*   cnt     = cur + Nn;                 // Nn
    int*   incl    = cnt + Nn;                 // Nn
    int*   bsum    = incl + Nn;                // NSB
    int*   bofs    = bsum + NSB;               // NSB
    unsigned* mm   = (unsigned*)(bofs + NSB);  // 8 (2 per pass)

    prep<<<(NB + 255) / 256, 256, 0, stream>>>(x, nt, xb, thr, cnt, mm);
    hist<<<(Ee + 255) / 256, 256, 0, stream>>>(dstv, cnt);
    scan1<<<NSB, SCAN_BLK, 0, stream>>>(cnt, incl, bsum);
    scan2<<<1, 64, 0, stream>>>(bsum, bofs);
    scan3<<<(Nn + 255) / 256, 256, 0, stream>>>(cnt, incl, bofs, row, cur);
    build<<<(Ee + 255) / 256, 256, 0, stream>>>(srcv, dstv, ew, mult, cur, csr_src, csr_w);

    for (int p = 0; p < 4; p++) {
        gather<<<NB / 256, 256, 0, stream>>>(row, csr_src, csr_w, xb, aggr, mm + 2 * p);
        update<<<(NB + 255) / 256, 256, 0, stream>>>(aggr, thr, mm + 2 * p, xb);
    }

    final_k<<<1, 512, 0, stream>>>(xb, dix, fcw, fcb, out);
}

// Round 5
// 973.977 us; speedup vs baseline: 1.0813x; 1.0813x over previous
//
#include <hip/hip_runtime.h>

#define Bsz 16
#define Nn  100000
#define Ee  2000000
#define Dd  512
#define Cc  10
#define NB  (Nn * Bsz)
#define SCAN_BLK 1024
#define NSB ((Nn + SCAN_BLK - 1) / SCAN_BLK)   // 98

// ---- ordered-uint encoding for float atomic min/max ----
__device__ __forceinline__ unsigned enc_f(float f) {
    unsigned u = __float_as_uint(f);
    return (u & 0x80000000u) ? ~u : (u | 0x80000000u);
}
__device__ __forceinline__ float dec_f(unsigned e) {
    unsigned u = (e & 0x80000000u) ? (e ^ 0x80000000u) : ~e;
    return __uint_as_float(u);
}

// LDS-tiled transpose x (B,N) -> xb[n*16+b] (coalesced both sides);
// thr[n]=|nt[n]|; zero histogram; init 4 passes' minmax slots
__global__ void prep(const float* __restrict__ x, const float* __restrict__ nt,
                     float* __restrict__ xb, float* __restrict__ thr,
                     int* __restrict__ cnt, unsigned* __restrict__ mm) {
    __shared__ float sm[16][65];
    int t = threadIdx.x;
    int n0 = blockIdx.x * 64;
    #pragma unroll
    for (int rep = 0; rep < 4; rep++) {
        int r = rep * 4 + (t >> 6);      // batch row 0..15
        int c = t & 63;                  // node within tile
        int n = n0 + c;
        sm[r][c] = (n < Nn) ? x[r * Nn + n] : 0.0f;
    }
    __syncthreads();
    int nn = t >> 2, bq = t & 3;
    int n = n0 + nn;
    if (n < Nn) {
        float4 v;
        v.x = sm[bq * 4 + 0][nn];
        v.y = sm[bq * 4 + 1][nn];
        v.z = sm[bq * 4 + 2][nn];
        v.w = sm[bq * 4 + 3][nn];
        ((float4*)xb)[n * 4 + bq] = v;
    }
    int gid = blockIdx.x * 256 + t;
    if (gid < Nn) { thr[gid] = fabsf(nt[gid]); cnt[gid] = 0; }
    if (gid < 8)  { mm[gid] = (gid & 1) ? 0u : 0xFFFFFFFFu; }
}

__global__ void hist(const int* __restrict__ dstv, int* __restrict__ cnt) {
    int e = blockIdx.x * blockDim.x + threadIdx.x;
    if (e < Ee) atomicAdd(&cnt[dstv[e]], 1);
}

// per-block inclusive scan (Hillis-Steele) + block sums
__global__ void scan1(const int* __restrict__ cnt, int* __restrict__ incl,
                      int* __restrict__ bsum) {
    __shared__ int s[SCAN_BLK];
    int i = blockIdx.x * SCAN_BLK + threadIdx.x;
    int v = (i < Nn) ? cnt[i] : 0;
    s[threadIdx.x] = v;
    __syncthreads();
    for (int off = 1; off < SCAN_BLK; off <<= 1) {
        int t = (threadIdx.x >= off) ? s[threadIdx.x - off] : 0;
        __syncthreads();
        s[threadIdx.x] += t;
        __syncthreads();
    }
    if (i < Nn) incl[i] = s[threadIdx.x];
    if (threadIdx.x == SCAN_BLK - 1) bsum[blockIdx.x] = s[threadIdx.x];
}

__global__ void scan2(const int* __restrict__ bsum, int* __restrict__ bofs) {
    if (threadIdx.x == 0) {
        int acc = 0;
        for (int k = 0; k < NSB; k++) { bofs[k] = acc; acc += bsum[k]; }
    }
}

// exclusive row offsets + scatter cursors
__global__ void scan3(const int* __restrict__ cnt, const int* __restrict__ incl,
                      const int* __restrict__ bofs, int* __restrict__ row,
                      int* __restrict__ cur) {
    int i = blockIdx.x * blockDim.x + threadIdx.x;
    if (i < Nn) {
        int excl = incl[i] - cnt[i] + bofs[i / SCAN_BLK];
        row[i] = excl;
        cur[i] = excl;
    }
    if (i == 0) row[Nn] = Ee;
}

// permute edges into CSR-by-dst; fold in w = ew * tanh(mult) (computed once total)
__global__ void build(const int* __restrict__ srcv, const int* __restrict__ dstv,
                      const float* __restrict__ ew, const float* __restrict__ mult,
                      int* __restrict__ cur, int* __restrict__ csr_src,
                      float* __restrict__ csr_w) {
    int e = blockIdx.x * blockDim.x + threadIdx.x;
    if (e < Ee) {
        int d = dstv[e];
        int pos = atomicAdd(&cur[d], 1);
        csr_src[pos] = srcv[e];
        csr_w[pos]   = ew[e] * tanhf(mult[e]);
    }
}

// thread = (node, batch): 8-wide unrolled edge loop -> 8 independent load
// chains in flight per lane (latency-bound fix). Clamped indices, no tail.
__global__ void gather(const int* __restrict__ row, const int* __restrict__ csr_src,
                       const float* __restrict__ csr_w, const float* __restrict__ xb,
                       float* __restrict__ aggr, unsigned* __restrict__ mm) {
    int i = blockIdx.x * 256 + threadIdx.x;   // grid exact: NB/256 blocks
    int n = i >> 4, b = i & 15;
    int ks = row[n], ke = row[n + 1];
    float acc = 0.0f;
    for (int k = ks; k < ke; k += 8) {
        int   s[8];
        float w[8], v[8];
        #pragma unroll
        for (int j = 0; j < 8; ++j) {
            int kk = k + j;
            int kc = kk < ke ? kk : ks;          // always a valid index
            s[j] = csr_src[kc];
            float wv = csr_w[kc];
            w[j] = kk < ke ? wv : 0.0f;          // dead slots contribute 0
        }
        #pragma unroll
        for (int j = 0; j < 8; ++j) v[j] = xb[s[j] * 16 + b];
        #pragma unroll
        for (int j = 0; j < 8; ++j) acc += v[j] * w[j];
    }
    aggr[i] = acc;

    float lmin = acc, lmax = acc;
    #pragma unroll
    for (int off = 32; off > 0; off >>= 1) {
        lmin = fminf(lmin, __shfl_down(lmin, off));
        lmax = fmaxf(lmax, __shfl_down(lmax, off));
    }
    __shared__ float smin[4], smax[4];
    int wid = threadIdx.x >> 6, lane = threadIdx.x & 63;
    if (lane == 0) { smin[wid] = lmin; smax[wid] = lmax; }
    __syncthreads();
    if (threadIdx.x == 0) {
        float m0 = smin[0], M0 = smax[0];
        #pragma unroll
        for (int k = 1; k < 4; k++) { m0 = fminf(m0, smin[k]); M0 = fmaxf(M0, smax[k]); }
        atomicMin(&mm[0], enc_f(m0));
        atomicMax(&mm[1], enc_f(M0));
    }
}

// float4-vectorized sigmoid update
__global__ void update(const float* __restrict__ aggr, const float* __restrict__ thr,
                       const unsigned* __restrict__ mm, float* __restrict__ xb) {
    int q = blockIdx.x * blockDim.x + threadIdx.x;   // NB/4 quads
    if (q < NB / 4) {
        float amin = dec_f(mm[0]), amax = dec_f(mm[1]);
        float inv = 1.0f / (amax - amin);
        int n = q >> 2;
        float t = thr[n];
        float4 a = ((const float4*)aggr)[q];
        float4 r;
        r.x = 1.0f / (1.0f + expf(-((a.x - amin) * inv - t)));
        r.y = 1.0f / (1.0f + expf(-((a.y - amin) * inv - t)));
        r.z = 1.0f / (1.0f + expf(-((a.z - amin) * inv - t)));
        r.w = 1.0f / (1.0f + expf(-((a.w - amin) * inv - t)));
        ((float4*)xb)[q] = r;
    }
}

// gather decision nodes + (16x512)@(512x10) matmul, single block of 512 threads
__global__ void final_k(const float* __restrict__ xb, const int* __restrict__ dix,
                        const float* __restrict__ fcw, const float* __restrict__ fcb,
                        float* __restrict__ out) {
    __shared__ float xd[Dd][Bsz];   // 32 KB
    int j = threadIdx.x;
    int n = dix[j];
    #pragma unroll
    for (int b = 0; b < Bsz; b++) xd[j][b] = xb[n * 16 + b];
    __syncthreads();
    if (j < Bsz * Cc) {
        int b = j / Cc, c = j % Cc;
        float acc = fcb[c];
        for (int k = 0; k < Dd; k++) acc += xd[k][b] * fcw[c * Dd + k];
        out[b * Cc + c] = acc;
    }
}

extern "C" void kernel_launch(void* const* d_in, const int* in_sizes, int n_in,
                              void* d_out, int out_size, void* d_ws, size_t ws_size,
                              hipStream_t stream) {
    const float* x    = (const float*)d_in[0];
    const float* ew   = (const float*)d_in[1];
    const float* mult = (const float*)d_in[2];
    const float* nt   = (const float*)d_in[3];
    const float* fcw  = (const float*)d_in[4];
    const float* fcb  = (const float*)d_in[5];
    const int*   ei   = (const int*)d_in[6];
    const int*   dix  = (const int*)d_in[7];
    float* out = (float*)d_out;

    const int* srcv = ei;
    const int* dstv = ei + Ee;

    // workspace layout (~31 MB, proven to fit)
    float* xb      = (float*)d_ws;             // NB
    float* aggr    = xb + NB;                  // NB
    float* thr     = aggr + NB;                // Nn
    float* csr_w   = thr + Nn;                 // Ee
    int*   csr_src = (int*)(csr_w + Ee);       // Ee
    int*   row     = csr_src + Ee;             // Nn+1
    int*   cur     = row + Nn + 1;             // Nn
    int*   cnt     = cur + Nn;                 // Nn
    int*   incl    = cnt + Nn;                 // Nn
    int*   bsum    = incl + Nn;                // NSB
    int*   bofs    = bsum + NSB;               // NSB
    unsigned* mm   = (unsigned*)(bofs + NSB);  // 8 (2 per pass)

    prep<<<(Nn + 63) / 64, 256, 0, stream>>>(x, nt, xb, thr, cnt, mm);
    hist<<<(Ee + 255) / 256, 256, 0, stream>>>(dstv, cnt);
    scan1<<<NSB, SCAN_BLK, 0, stream>>>(cnt, incl, bsum);
    scan2<<<1, 64, 0, stream>>>(bsum, bofs);
    scan3<<<(Nn + 255) / 256, 256, 0, stream>>>(cnt, incl, bofs, row, cur);
    build<<<(Ee + 255) / 256, 256, 0, stream>>>(srcv, dstv, ew, mult, cur, csr_src, csr_w);

    for (int p = 0; p < 4; p++) {
        gather<<<NB / 256, 256, 0, stream>>>(row, csr_src, csr_w, xb, aggr, mm + 2 * p);
        update<<<(NB / 4 + 255) / 256, 256, 0, stream>>>(aggr, thr, mm + 2 * p, xb);
    }

    final_k<<<1, 512, 0, stream>>>(xb, dix, fcw, fcb, out);
}

// Round 6
// 495.198 us; speedup vs baseline: 2.1267x; 1.9668x over previous
//
#include <hip/hip_runtime.h>

#define Bsz 16
#define Nn  100000
#define Ee  2000000
#define Dd  512
#define Cc  10
#define NB  (Nn * Bsz)
#define SCAN_BLK 1024
#define NSB ((Nn + SCAN_BLK - 1) / SCAN_BLK)   // 98
#define NPARTS (NB / 256)                       // 6250 gather blocks

// ---- ordered-uint encoding for float min/max (monotone map) ----
__device__ __forceinline__ unsigned enc_f(float f) {
    unsigned u = __float_as_uint(f);
    return (u & 0x80000000u) ? ~u : (u | 0x80000000u);
}
__device__ __forceinline__ float dec_f(unsigned e) {
    unsigned u = (e & 0x80000000u) ? (e ^ 0x80000000u) : ~e;
    return __uint_as_float(u);
}

// LDS-tiled transpose x (B,N) -> xb[n*16+b] (coalesced both sides);
// thr[n]=|nt[n]|; zero histogram
__global__ void prep(const float* __restrict__ x, const float* __restrict__ nt,
                     float* __restrict__ xb, float* __restrict__ thr,
                     int* __restrict__ cnt) {
    __shared__ float sm[16][65];
    int t = threadIdx.x;
    int n0 = blockIdx.x * 64;
    #pragma unroll
    for (int rep = 0; rep < 4; rep++) {
        int r = rep * 4 + (t >> 6);      // batch row 0..15
        int c = t & 63;                  // node within tile
        int n = n0 + c;
        sm[r][c] = (n < Nn) ? x[r * Nn + n] : 0.0f;
    }
    __syncthreads();
    int nn = t >> 2, bq = t & 3;
    int n = n0 + nn;
    if (n < Nn) {
        float4 v;
        v.x = sm[bq * 4 + 0][nn];
        v.y = sm[bq * 4 + 1][nn];
        v.z = sm[bq * 4 + 2][nn];
        v.w = sm[bq * 4 + 3][nn];
        ((float4*)xb)[n * 4 + bq] = v;
    }
    int gid = blockIdx.x * 256 + t;
    if (gid < Nn) { thr[gid] = fabsf(nt[gid]); cnt[gid] = 0; }
}

__global__ void hist(const int* __restrict__ dstv, int* __restrict__ cnt) {
    int e = blockIdx.x * blockDim.x + threadIdx.x;
    if (e < Ee) atomicAdd(&cnt[dstv[e]], 1);
}

// per-block inclusive scan (Hillis-Steele) + block sums
__global__ void scan1(const int* __restrict__ cnt, int* __restrict__ incl,
                      int* __restrict__ bsum) {
    __shared__ int s[SCAN_BLK];
    int i = blockIdx.x * SCAN_BLK + threadIdx.x;
    int v = (i < Nn) ? cnt[i] : 0;
    s[threadIdx.x] = v;
    __syncthreads();
    for (int off = 1; off < SCAN_BLK; off <<= 1) {
        int t = (threadIdx.x >= off) ? s[threadIdx.x - off] : 0;
        __syncthreads();
        s[threadIdx.x] += t;
        __syncthreads();
    }
    if (i < Nn) incl[i] = s[threadIdx.x];
    if (threadIdx.x == SCAN_BLK - 1) bsum[blockIdx.x] = s[threadIdx.x];
}

__global__ void scan2(const int* __restrict__ bsum, int* __restrict__ bofs) {
    if (threadIdx.x == 0) {
        int acc = 0;
        for (int k = 0; k < NSB; k++) { bofs[k] = acc; acc += bsum[k]; }
    }
}

// exclusive row offsets + scatter cursors
__global__ void scan3(const int* __restrict__ cnt, const int* __restrict__ incl,
                      const int* __restrict__ bofs, int* __restrict__ row,
                      int* __restrict__ cur) {
    int i = blockIdx.x * blockDim.x + threadIdx.x;
    if (i < Nn) {
        int excl = incl[i] - cnt[i] + bofs[i / SCAN_BLK];
        row[i] = excl;
        cur[i] = excl;
    }
    if (i == 0) row[Nn] = Ee;
}

// permute edges into CSR-by-dst; ONE paired 8B store per edge (halves
// scattered-write line touches vs two 4B stores to separate arrays)
__global__ void build(const int* __restrict__ srcv, const int* __restrict__ dstv,
                      const float* __restrict__ ew, const float* __restrict__ mult,
                      int* __restrict__ cur, int2* __restrict__ csr_sw) {
    int e = blockIdx.x * blockDim.x + threadIdx.x;
    if (e < Ee) {
        int d = dstv[e];
        int pos = atomicAdd(&cur[d], 1);
        int2 p;
        p.x = srcv[e];
        p.y = __float_as_int(ew[e] * tanhf(mult[e]));
        csr_sw[pos] = p;
    }
}

// thread = (node, batch): 8-wide unrolled edge loop (8 paired CSR loads then
// 8 xb-line loads in flight). No contended global atomics: per-block min/max
// partial is a plain store, folded by mm_reduce.
__global__ void gather(const int* __restrict__ row, const int2* __restrict__ csr_sw,
                       const float* __restrict__ xb, float* __restrict__ aggr,
                       uint2* __restrict__ part) {
    int i = blockIdx.x * 256 + threadIdx.x;   // grid exact: NPARTS blocks
    int n = i >> 4, b = i & 15;
    int ks = row[n], ke = row[n + 1];
    float acc = 0.0f;
    for (int k = ks; k < ke; k += 8) {
        int2  p[8];
        float v[8];
        #pragma unroll
        for (int j = 0; j < 8; ++j) {
            int kk = k + j;
            int kc = kk < ke ? kk : ks;          // always a valid index
            p[j] = csr_sw[kc];
            if (kk >= ke) p[j].y = 0;            // 0.0f weight for dead slots
        }
        #pragma unroll
        for (int j = 0; j < 8; ++j) v[j] = xb[p[j].x * 16 + b];
        #pragma unroll
        for (int j = 0; j < 8; ++j) acc += v[j] * __int_as_float(p[j].y);
    }
    aggr[i] = acc;

    float lmin = acc, lmax = acc;
    #pragma unroll
    for (int off = 32; off > 0; off >>= 1) {
        lmin = fminf(lmin, __shfl_down(lmin, off));
        lmax = fmaxf(lmax, __shfl_down(lmax, off));
    }
    __shared__ float smin[4], smax[4];
    int wid = threadIdx.x >> 6, lane = threadIdx.x & 63;
    if (lane == 0) { smin[wid] = lmin; smax[wid] = lmax; }
    __syncthreads();
    if (threadIdx.x == 0) {
        float m0 = smin[0], M0 = smax[0];
        #pragma unroll
        for (int k = 1; k < 4; k++) { m0 = fminf(m0, smin[k]); M0 = fmaxf(M0, smax[k]); }
        part[blockIdx.x] = make_uint2(enc_f(m0), enc_f(M0));   // plain store
    }
}

// fold 6250 per-block partials -> mm[0]=min, mm[1]=max. One block, no atomics.
__global__ void mm_reduce(const uint2* __restrict__ part, unsigned* __restrict__ mm) {
    unsigned lmin = 0xFFFFFFFFu, lmax = 0u;
    for (int i = threadIdx.x; i < NPARTS; i += 1024) {
        uint2 p = part[i];
        lmin = min(lmin, p.x);
        lmax = max(lmax, p.y);
    }
    #pragma unroll
    for (int off = 32; off > 0; off >>= 1) {
        lmin = min(lmin, __shfl_down(lmin, off));
        lmax = max(lmax, __shfl_down(lmax, off));
    }
    __shared__ unsigned smn[16], smx[16];
    int wid = threadIdx.x >> 6, lane = threadIdx.x & 63;
    if (lane == 0) { smn[wid] = lmin; smx[wid] = lmax; }
    __syncthreads();
    if (threadIdx.x == 0) {
        #pragma unroll
        for (int k = 1; k < 16; k++) { lmin = min(lmin, smn[k]); lmax = max(lmax, smx[k]); }
        mm[0] = lmin;
        mm[1] = lmax;
    }
}

// float4-vectorized sigmoid update
__global__ void update(const float* __restrict__ aggr, const float* __restrict__ thr,
                       const unsigned* __restrict__ mm, float* __restrict__ xb) {
    int q = blockIdx.x * blockDim.x + threadIdx.x;   // NB/4 quads
    if (q < NB / 4) {
        float amin = dec_f(mm[0]), amax = dec_f(mm[1]);
        float inv = 1.0f / (amax - amin);
        int n = q >> 2;
        float t = thr[n];
        float4 a = ((const float4*)aggr)[q];
        float4 r;
        r.x = 1.0f / (1.0f + expf(-((a.x - amin) * inv - t)));
        r.y = 1.0f / (1.0f + expf(-((a.y - amin) * inv - t)));
        r.z = 1.0f / (1.0f + expf(-((a.z - amin) * inv - t)));
        r.w = 1.0f / (1.0f + expf(-((a.w - amin) * inv - t)));
        ((float4*)xb)[q] = r;
    }
}

// gather decision nodes + (16x512)@(512x10) matmul, single block of 512 threads
__global__ void final_k(const float* __restrict__ xb, const int* __restrict__ dix,
                        const float* __restrict__ fcw, const float* __restrict__ fcb,
                        float* __restrict__ out) {
    __shared__ float xd[Dd][Bsz];   // 32 KB
    int j = threadIdx.x;
    int n = dix[j];
    #pragma unroll
    for (int b = 0; b < Bsz; b++) xd[j][b] = xb[n * 16 + b];
    __syncthreads();
    if (j < Bsz * Cc) {
        int b = j / Cc, c = j % Cc;
        float acc = fcb[c];
        for (int k = 0; k < Dd; k++) acc += xd[k][b] * fcw[c * Dd + k];
        out[b * Cc + c] = acc;
    }
}

extern "C" void kernel_launch(void* const* d_in, const int* in_sizes, int n_in,
                              void* d_out, int out_size, void* d_ws, size_t ws_size,
                              hipStream_t stream) {
    const float* x    = (const float*)d_in[0];
    const float* ew   = (const float*)d_in[1];
    const float* mult = (const float*)d_in[2];
    const float* nt   = (const float*)d_in[3];
    const float* fcw  = (const float*)d_in[4];
    const float* fcb  = (const float*)d_in[5];
    const int*   ei   = (const int*)d_in[6];
    const int*   dix  = (const int*)d_in[7];
    float* out = (float*)d_out;

    const int* srcv = ei;
    const int* dstv = ei + Ee;

    // workspace layout (~31.6 MB)
    float* xb      = (float*)d_ws;              // NB
    float* aggr    = xb + NB;                   // NB
    float* thr     = aggr + NB;                 // Nn
    int2*  csr_sw  = (int2*)(thr + Nn);         // Ee (8B aligned: offset even)
    uint2* part    = (uint2*)(csr_sw + Ee);     // NPARTS (8B aligned)
    int*   row     = (int*)(part + NPARTS);     // Nn+1
    int*   cur     = row + Nn + 1;              // Nn
    int*   cnt     = cur + Nn;                  // Nn
    int*   incl    = cnt + Nn;                  // Nn
    int*   bsum    = incl + Nn;                 // NSB
    int*   bofs    = bsum + NSB;                // NSB
    unsigned* mm   = (unsigned*)(bofs + NSB);   // 2

    prep<<<(Nn + 63) / 64, 256, 0, stream>>>(x, nt, xb, thr, cnt);
    hist<<<(Ee + 255) / 256, 256, 0, stream>>>(dstv, cnt);
    scan1<<<NSB, SCAN_BLK, 0, stream>>>(cnt, incl, bsum);
    scan2<<<1, 64, 0, stream>>>(bsum, bofs);
    scan3<<<(Nn + 255) / 256, 256, 0, stream>>>(cnt, incl, bofs, row, cur);
    build<<<(Ee + 255) / 256, 256, 0, stream>>>(srcv, dstv, ew, mult, cur, csr_sw);

    for (int p = 0; p < 4; p++) {
        gather<<<NPARTS, 256, 0, stream>>>(row, csr_sw, xb, aggr, part);
        mm_reduce<<<1, 1024, 0, stream>>>(part, mm);
        update<<<(NB / 4 + 255) / 256, 256, 0, stream>>>(aggr, thr, mm, xb);
    }

    final_k<<<1, 512, 0, stream>>>(xb, dix, fcw, fcb, out);
}